// Round 1
// baseline (296.082 us; speedup 1.0000x reference)
//
#include <hip/hip_runtime.h>
#include <cstdint>

// IDCT (DCT-III) of 4096x4096 fp32 along last dim, cast as bf16 MFMA GEMM:
//   Y = X * C^T,  C[k][n] = w_n * cos(pi*n*(2k+1)/(2N)), w_0=1, w_n=2.
// C is generated on-device into d_ws (it is a pure function of indices).

#define NN 4096
#define BM 128
#define BN 128
#define BK 64

typedef __bf16  bf16x8 __attribute__((ext_vector_type(8)));
typedef float   f32x4  __attribute__((ext_vector_type(4)));

// fp32 -> bf16 round-to-nearest-even (inputs are finite; no NaN path needed)
__device__ __forceinline__ unsigned short f2bf(float f) {
    unsigned int u = __float_as_uint(f);
    unsigned int r = u + 0x7fffu + ((u >> 16) & 1u);
    return (unsigned short)(r >> 16);
}

// async global->LDS, 16B per lane (HW: LDS dest = wave-uniform base + lane*16)
__device__ __forceinline__ void async_copy16(void* lds_base, const void* gptr) {
    __builtin_amdgcn_global_load_lds(
        (const __attribute__((address_space(1))) unsigned int*)gptr,
        (__attribute__((address_space(3))) unsigned int*)lds_base,
        16, 0, 0);
}

// ---- kernel 1: X fp32 -> bf16 (vectorized 4 elems/thread) ----
__global__ __launch_bounds__(256) void cvt_f32_bf16(const float* __restrict__ x,
                                                    unsigned short* __restrict__ y) {
    int i = blockIdx.x * 256 + threadIdx.x;            // over NN*NN/4
    float4 v = ((const float4*)x)[i];
    ushort4 o;
    o.x = f2bf(v.x); o.y = f2bf(v.y); o.z = f2bf(v.z); o.w = f2bf(v.w);
    ((ushort4*)y)[i] = o;
}

// ---- kernel 2: generate C[k][n] in bf16, row-major (B^T layout for GEMM) ----
__global__ __launch_bounds__(256) void gen_cos(unsigned short* __restrict__ Cb) {
    int i = blockIdx.x * 256 + threadIdx.x;            // over NN*(NN/4)
    int kout = i >> 10;                                // NN/4 = 1024 groups per row
    int n0 = (i & 1023) * 4;
    int twok1 = 2 * kout + 1;
    const float s = 3.834951969714103e-4f;             // pi / 8192
    ushort4 o;
    unsigned short* po = (unsigned short*)&o;
#pragma unroll
    for (int j = 0; j < 4; ++j) {
        int n = n0 + j;
        int p = (n * twok1) & 16383;                   // phase mod 2*pi
        float c = __cosf((float)p * s);
        float w = (n == 0) ? 1.0f : 2.0f;
        po[j] = f2bf(w * c);
    }
    ((ushort4*)Cb)[i] = o;
}

// ---- kernel 3: bf16 GEMM, out[r][k] = sum_n A[r][n] * B[k][n] (B^T input) ----
// 128x128 tile, BK=64, 4 waves in 2x2, each wave 4x4 grid of 16x16x32 MFMA.
__global__ __launch_bounds__(256) void idct_gemm(const unsigned short* __restrict__ A,
                                                 const unsigned short* __restrict__ B,
                                                 float* __restrict__ C) {
    __shared__ __align__(16) unsigned short sA[BM * BK];   // 16 KB
    __shared__ __align__(16) unsigned short sB[BN * BK];   // 16 KB

    const int tid  = threadIdx.x;
    const int wave = tid >> 6;
    const int lane = tid & 63;
    const int waveM = wave >> 1;
    const int waveN = wave & 1;

    const int rowBase = blockIdx.y * BM;
    const int colBase = blockIdx.x * BN;

    f32x4 acc[4][4] = {};

    // staging geometry: chunk = 1 KB = 8 rows of 128B; 16 chunks per tile
    const int srow = lane >> 3;          // row within chunk
    const int scol = (lane & 7) * 8;     // elem offset (16B granules)

    for (int k0 = 0; k0 < NN; k0 += BK) {
#pragma unroll
        for (int j = 0; j < 4; ++j) {
            int ck = wave * 4 + j;               // 0..15
            int r  = ck * 8 + srow;              // 0..127
            const unsigned short* ga = A + (size_t)(rowBase + r) * NN + k0 + scol;
            async_copy16(&sA[ck * 512], ga);
            const unsigned short* gb = B + (size_t)(colBase + r) * NN + k0 + scol;
            async_copy16(&sB[ck * 512], gb);
        }
        __syncthreads();

#pragma unroll
        for (int kk = 0; kk < 2; ++kk) {
            const int koff = kk * 32 + (lane >> 4) * 8;
            bf16x8 af[4], bfr[4];
#pragma unroll
            for (int mi = 0; mi < 4; ++mi) {
                int r = waveM * 64 + mi * 16 + (lane & 15);
                af[mi] = *(const bf16x8*)&sA[r * BK + koff];
            }
#pragma unroll
            for (int ni = 0; ni < 4; ++ni) {
                int r = waveN * 64 + ni * 16 + (lane & 15);
                bfr[ni] = *(const bf16x8*)&sB[r * BK + koff];
            }
#pragma unroll
            for (int mi = 0; mi < 4; ++mi)
#pragma unroll
                for (int ni = 0; ni < 4; ++ni)
                    acc[mi][ni] = __builtin_amdgcn_mfma_f32_16x16x32_bf16(
                        af[mi], bfr[ni], acc[mi][ni], 0, 0, 0);
        }
        __syncthreads();
    }

    // epilogue: C/D layout col = lane&15, row = (lane>>4)*4 + reg  [m89-verified]
    const int mrow0 = rowBase + waveM * 64 + (lane >> 4) * 4;
    const int ncol0 = colBase + waveN * 64 + (lane & 15);
#pragma unroll
    for (int mi = 0; mi < 4; ++mi)
#pragma unroll
        for (int ni = 0; ni < 4; ++ni)
#pragma unroll
            for (int rg = 0; rg < 4; ++rg) {
                int rr = mrow0 + mi * 16 + rg;
                int cc = ncol0 + ni * 16;
                C[(size_t)rr * NN + cc] = acc[mi][ni][rg];
            }
}

// ---- fallback: direct O(N^2) eval (only if ws_size is too small) ----
__global__ __launch_bounds__(256) void idct_naive(const float* __restrict__ x,
                                                  float* __restrict__ out) {
    int row = blockIdx.x;
    __shared__ float sx[NN];
    for (int i = threadIdx.x; i < NN; i += 256) sx[i] = x[(size_t)row * NN + i];
    __syncthreads();
    const float s = 3.834951969714103e-4f;  // pi / 8192
    for (int k = threadIdx.x; k < NN; k += 256) {
        int twok1 = 2 * k + 1;
        float acc = sx[0];
        int p = 0;
        for (int n = 1; n < NN; ++n) {
            p += twok1; p &= 16383;
            acc += 2.0f * sx[n] * __cosf((float)p * s);
        }
        out[(size_t)row * NN + k] = acc;
    }
}

extern "C" void kernel_launch(void* const* d_in, const int* in_sizes, int n_in,
                              void* d_out, int out_size, void* d_ws, size_t ws_size,
                              hipStream_t stream) {
    const float* x = (const float*)d_in[0];
    float* out = (float*)d_out;

    const size_t elems = (size_t)NN * NN;
    const size_t need = 2 * elems * sizeof(unsigned short);  // 64 MB

    if (ws_size >= need) {
        unsigned short* Abf = (unsigned short*)d_ws;
        unsigned short* Cbf = Abf + elems;

        cvt_f32_bf16<<<elems / 4 / 256, 256, 0, stream>>>(x, Abf);
        gen_cos<<<elems / 4 / 256, 256, 0, stream>>>(Cbf);

        dim3 grid(NN / BN, NN / BM);
        idct_gemm<<<grid, 256, 0, stream>>>(Abf, Cbf, out);
    } else {
        idct_naive<<<NN, 256, 0, stream>>>(x, out);
    }
}

// Round 2
// 261.074 us; speedup vs baseline: 1.1341x; 1.1341x over previous
//
#include <hip/hip_runtime.h>
#include <cstdint>

// IDCT (DCT-III) of 4096x4096 fp32 along last dim, cast as bf16 MFMA GEMM:
//   Y = X * C^T,  C[k][n] = w_n * cos(pi*n*(2k+1)/(2N)), w_0=1, w_n=2.
// C is generated on-device into d_ws (pure function of indices).
//
// R2: XOR-swizzled LDS layout. Logical 16B granule g of row r lives at
// physical granule g^(r&7). Baked into the global fetch column (LDS slot is
// HW-fixed at base+lane*16 for global_load_lds), unwound at ds_read time.
// Kills the 16-way bank conflict of the 128B-row-stride layout (R1:
// SQ_LDS_BANK_CONFLICT=5e7).

#define NN 4096
#define BM 128
#define BN 128
#define BK 64

typedef __bf16  bf16x8 __attribute__((ext_vector_type(8)));
typedef float   f32x4  __attribute__((ext_vector_type(4)));

// fp32 -> bf16 round-to-nearest-even (inputs finite; no NaN path needed)
__device__ __forceinline__ unsigned short f2bf(float f) {
    unsigned int u = __float_as_uint(f);
    unsigned int r = u + 0x7fffu + ((u >> 16) & 1u);
    return (unsigned short)(r >> 16);
}

// async global->LDS, 16B per lane (HW: LDS dest = wave-uniform base + lane*16)
__device__ __forceinline__ void async_copy16(void* lds_base, const void* gptr) {
    __builtin_amdgcn_global_load_lds(
        (const __attribute__((address_space(1))) unsigned int*)gptr,
        (__attribute__((address_space(3))) unsigned int*)lds_base,
        16, 0, 0);
}

// ---- prep: block 0..16383 converts X fp32->bf16; 16384..32767 generates C ----
__global__ __launch_bounds__(256) void prep(const float* __restrict__ x,
                                            unsigned short* __restrict__ Abf,
                                            unsigned short* __restrict__ Cbf) {
    int b = blockIdx.x;
    if (b < 16384) {
        int i = b * 256 + threadIdx.x;                 // over NN*NN/4
        float4 v = ((const float4*)x)[i];
        ushort4 o;
        o.x = f2bf(v.x); o.y = f2bf(v.y); o.z = f2bf(v.z); o.w = f2bf(v.w);
        ((ushort4*)Abf)[i] = o;
    } else {
        int i = (b - 16384) * 256 + threadIdx.x;       // over NN*(NN/4)
        int kout = i >> 10;                            // 1024 groups per row
        int n0 = (i & 1023) * 4;
        int twok1 = 2 * kout + 1;
        const float s = 3.834951969714103e-4f;         // pi / 8192
        ushort4 o;
        unsigned short* po = (unsigned short*)&o;
#pragma unroll
        for (int j = 0; j < 4; ++j) {
            int n = n0 + j;
            int p = (n * twok1) & 16383;               // phase mod 2*pi
            float c = __cosf((float)p * s);
            float w = (n == 0) ? 1.0f : 2.0f;
            po[j] = f2bf(w * c);
        }
        ((ushort4*)Cbf)[i] = o;
    }
}

// ---- bf16 GEMM, out[r][k] = sum_n A[r][n] * B[k][n] (B^T input) ----
// 128x128 tile, BK=64, 4 waves in 2x2, each wave 4x4 grid of 16x16x32 MFMA.
__global__ __launch_bounds__(256) void idct_gemm(const unsigned short* __restrict__ A,
                                                 const unsigned short* __restrict__ B,
                                                 float* __restrict__ C) {
    __shared__ __align__(16) unsigned short sA[BM * BK];   // 16 KB
    __shared__ __align__(16) unsigned short sB[BN * BK];   // 16 KB

    const int tid  = threadIdx.x;
    const int wave = tid >> 6;
    const int lane = tid & 63;
    const int waveM = wave >> 1;
    const int waveN = wave & 1;

    const int rowBase = blockIdx.y * BM;
    const int colBase = blockIdx.x * BN;

    f32x4 acc[4][4] = {};

    // staging geometry: chunk = 1 KB = 8 rows x 8 granules(16B); 16 chunks/tile
    const int srow  = lane >> 3;             // row within chunk (== r&7)
    const int sgran = lane & 7;              // physical granule this lane fills
    const int ggcol = (sgran ^ srow) * 8;    // logical granule -> global col (shorts)

    // fragment-read swizzle terms
    const int rmod = lane & 7;               // r&7 for this lane's fragment rows
    const int quad = lane >> 4;

    for (int k0 = 0; k0 < NN; k0 += BK) {
#pragma unroll
        for (int j = 0; j < 4; ++j) {
            int ck = wave * 4 + j;               // 0..15
            int r  = ck * 8 + srow;              // 0..127
            const unsigned short* ga = A + (size_t)(rowBase + r) * NN + k0 + ggcol;
            async_copy16(&sA[ck * 512], ga);
            const unsigned short* gb = B + (size_t)(colBase + r) * NN + k0 + ggcol;
            async_copy16(&sB[ck * 512], gb);
        }
        __syncthreads();

#pragma unroll
        for (int kk = 0; kk < 2; ++kk) {
            // logical granule g = kk*4 + quad; physical p = g ^ (r&7)
            const int poff = ((kk * 4 + quad) ^ rmod) * 8;   // shorts
            bf16x8 af[4], bfr[4];
#pragma unroll
            for (int mi = 0; mi < 4; ++mi) {
                int r = waveM * 64 + mi * 16 + (lane & 15);
                af[mi] = *(const bf16x8*)&sA[r * BK + poff];
            }
#pragma unroll
            for (int ni = 0; ni < 4; ++ni) {
                int r = waveN * 64 + ni * 16 + (lane & 15);
                bfr[ni] = *(const bf16x8*)&sB[r * BK + poff];
            }
#pragma unroll
            for (int mi = 0; mi < 4; ++mi)
#pragma unroll
                for (int ni = 0; ni < 4; ++ni)
                    acc[mi][ni] = __builtin_amdgcn_mfma_f32_16x16x32_bf16(
                        af[mi], bfr[ni], acc[mi][ni], 0, 0, 0);
        }
        __syncthreads();
    }

    // epilogue: C/D layout col = lane&15, row = (lane>>4)*4 + reg  [m89-verified]
    const int mrow0 = rowBase + waveM * 64 + (lane >> 4) * 4;
    const int ncol0 = colBase + waveN * 64 + (lane & 15);
#pragma unroll
    for (int mi = 0; mi < 4; ++mi)
#pragma unroll
        for (int ni = 0; ni < 4; ++ni)
#pragma unroll
            for (int rg = 0; rg < 4; ++rg) {
                int rr = mrow0 + mi * 16 + rg;
                int cc = ncol0 + ni * 16;
                C[(size_t)rr * NN + cc] = acc[mi][ni][rg];
            }
}

// ---- fallback: direct O(N^2) eval (only if ws_size is too small) ----
__global__ __launch_bounds__(256) void idct_naive(const float* __restrict__ x,
                                                  float* __restrict__ out) {
    int row = blockIdx.x;
    __shared__ float sx[NN];
    for (int i = threadIdx.x; i < NN; i += 256) sx[i] = x[(size_t)row * NN + i];
    __syncthreads();
    const float s = 3.834951969714103e-4f;  // pi / 8192
    for (int k = threadIdx.x; k < NN; k += 256) {
        int twok1 = 2 * k + 1;
        float acc = sx[0];
        int p = 0;
        for (int n = 1; n < NN; ++n) {
            p += twok1; p &= 16383;
            acc += 2.0f * sx[n] * __cosf((float)p * s);
        }
        out[(size_t)row * NN + k] = acc;
    }
}

extern "C" void kernel_launch(void* const* d_in, const int* in_sizes, int n_in,
                              void* d_out, int out_size, void* d_ws, size_t ws_size,
                              hipStream_t stream) {
    const float* x = (const float*)d_in[0];
    float* out = (float*)d_out;

    const size_t elems = (size_t)NN * NN;
    const size_t need = 2 * elems * sizeof(unsigned short);  // 64 MB

    if (ws_size >= need) {
        unsigned short* Abf = (unsigned short*)d_ws;
        unsigned short* Cbf = Abf + elems;

        prep<<<32768, 256, 0, stream>>>(x, Abf, Cbf);

        dim3 grid(NN / BN, NN / BM);
        idct_gemm<<<grid, 256, 0, stream>>>(Abf, Cbf, out);
    } else {
        idct_naive<<<NN, 256, 0, stream>>>(x, out);
    }
}

// Round 3
// 187.548 us; speedup vs baseline: 1.5787x; 1.3920x over previous
//
#include <hip/hip_runtime.h>
#include <cstdint>

// IDCT (DCT-III) of 4096x4096 fp32 along last dim as an int8 MFMA GEMM:
//   Y = X * C^T,  C[k][n] = w_n * cos(pi*n*(2k+1)/(2N)), w_0=1, w_n=2.
// R3: bf16 -> i8 (mfma_i32_16x16x64_i8, ~2x bf16 rate; i32 accum exact).
// Per-row A scales (s=rowmax/127), per-tensor B scale (2/127).
// Error budget: sigma~0.85, absmax ~4.7 << threshold 10.04.
// LDS: XOR-swizzled layout from R2 (granule g of row r at g^(r&7)) -> 0 bank
// conflicts (R2-verified). BK=128 i8 keeps 128B rows: identical geometry.

#define NN 4096
#define BM 128
#define BN 128
#define BK 128   // i8 elems; 128 B rows, same LDS footprint as R2

typedef int   i32x4 __attribute__((ext_vector_type(4)));

// async global->LDS, 16B per lane (HW: LDS dest = wave-uniform base + lane*16)
__device__ __forceinline__ void async_copy16(void* lds_base, const void* gptr) {
    __builtin_amdgcn_global_load_lds(
        (const __attribute__((address_space(1))) unsigned int*)gptr,
        (__attribute__((address_space(3))) unsigned int*)lds_base,
        16, 0, 0);
}

__device__ __forceinline__ int pack4(int q0, int q1, int q2, int q3) {
    return (q0 & 255) | ((q1 & 255) << 8) | ((q2 & 255) << 16) | ((q3 & 255) << 24);
}

// ---- prep: blocks 0..4095 quantize X rows to i8 (per-row scale);
//            blocks 4096..8191 generate C rows in i8 (scale 2/127) ----
__global__ __launch_bounds__(256) void prep_i8(const float* __restrict__ x,
                                               signed char* __restrict__ Aq,
                                               signed char* __restrict__ Bq,
                                               float* __restrict__ sArow) {
    __shared__ float red[256];
    const int b = blockIdx.x;
    const int t = threadIdx.x;

    if (b < 4096) {
        const float* xr = x + (size_t)b * NN;
        // thread t owns contiguous elements [t*16, t*16+16)
        float v[16];
#pragma unroll
        for (int j = 0; j < 4; ++j) {
            float4 f = ((const float4*)xr)[t * 4 + j];
            v[j * 4 + 0] = f.x; v[j * 4 + 1] = f.y;
            v[j * 4 + 2] = f.z; v[j * 4 + 3] = f.w;
        }
        float amax = 1e-30f;
#pragma unroll
        for (int j = 0; j < 16; ++j) amax = fmaxf(amax, __builtin_fabsf(v[j]));
        red[t] = amax;
        __syncthreads();
        for (int s = 128; s > 0; s >>= 1) {
            if (t < s) red[t] = fmaxf(red[t], red[t + s]);
            __syncthreads();
        }
        const float rmax = red[0];
        const float inv_s = 127.0f / rmax;
        int q[16];
#pragma unroll
        for (int j = 0; j < 16; ++j) q[j] = (int)rintf(v[j] * inv_s);
        i32x4 o;
        o[0] = pack4(q[0], q[1], q[2], q[3]);
        o[1] = pack4(q[4], q[5], q[6], q[7]);
        o[2] = pack4(q[8], q[9], q[10], q[11]);
        o[3] = pack4(q[12], q[13], q[14], q[15]);
        ((i32x4*)(Aq + (size_t)b * NN))[t] = o;
        if (t == 0) sArow[b] = rmax * (1.0f / 127.0f);
    } else {
        const int k = b - 4096;
        const int twok1 = 2 * k + 1;
        const float s = 3.834951969714103e-4f;   // pi / 8192
        int q[16];
#pragma unroll
        for (int j = 0; j < 16; ++j) {
            int n = t * 16 + j;
            int p = (n * twok1) & 16383;          // phase mod 2*pi (exact int)
            float c = __cosf((float)p * s);
            float w = (n == 0) ? 1.0f : 2.0f;
            q[j] = (int)rintf(w * c * 63.5f);     // scale 2/127
        }
        i32x4 o;
        o[0] = pack4(q[0], q[1], q[2], q[3]);
        o[1] = pack4(q[4], q[5], q[6], q[7]);
        o[2] = pack4(q[8], q[9], q[10], q[11]);
        o[3] = pack4(q[12], q[13], q[14], q[15]);
        ((i32x4*)(Bq + (size_t)k * NN))[t] = o;
    }
}

// ---- i8 GEMM: out[r][k] = sA[r]*sB * sum_n Aq[r][n]*Bq[k][n] ----
// 128x128 tile, BK=128, 4 waves 2x2, each wave 4x4 grid of 16x16x64 MFMA.
__global__ __launch_bounds__(256) void idct_gemm(const signed char* __restrict__ A,
                                                 const signed char* __restrict__ B,
                                                 const float* __restrict__ sArow,
                                                 float* __restrict__ C) {
    __shared__ __align__(16) signed char sA[BM * BK];   // 16 KB
    __shared__ __align__(16) signed char sB[BN * BK];   // 16 KB

    const int tid  = threadIdx.x;
    const int wave = tid >> 6;
    const int lane = tid & 63;
    const int waveM = wave >> 1;
    const int waveN = wave & 1;

    const int rowBase = blockIdx.y * BM;
    const int colBase = blockIdx.x * BN;

    i32x4 acc[4][4] = {};

    // staging: chunk = 1 KB = 8 rows x 8 granules(16B); 16 chunks per matrix
    const int srow  = lane >> 3;              // row within chunk (== r&7)
    const int sgran = lane & 7;               // physical granule this lane fills
    const int ggcol = (sgran ^ srow) * 16;    // swizzle baked into global col (bytes)

    const int rmod = lane & 7;                // r&7 for fragment rows
    const int quad = lane >> 4;

    for (int k0 = 0; k0 < NN; k0 += BK) {
#pragma unroll
        for (int j = 0; j < 4; ++j) {
            int ck = wave * 4 + j;                // 0..15
            int r  = ck * 8 + srow;               // 0..127
            const signed char* ga = A + (size_t)(rowBase + r) * NN + k0 + ggcol;
            async_copy16(&sA[ck * 1024], ga);
            const signed char* gb = B + (size_t)(colBase + r) * NN + k0 + ggcol;
            async_copy16(&sB[ck * 1024], gb);
        }
        __syncthreads();

#pragma unroll
        for (int kk = 0; kk < 2; ++kk) {
            // logical granule g = kk*4 + quad; physical p = g ^ (r&7)
            const int poff = ((kk * 4 + quad) ^ rmod) * 16;   // bytes
            i32x4 af[4], bfr[4];
#pragma unroll
            for (int mi = 0; mi < 4; ++mi) {
                int r = waveM * 64 + mi * 16 + (lane & 15);
                af[mi] = *(const i32x4*)&sA[r * BK + poff];
            }
#pragma unroll
            for (int ni = 0; ni < 4; ++ni) {
                int r = waveN * 64 + ni * 16 + (lane & 15);
                bfr[ni] = *(const i32x4*)&sB[r * BK + poff];
            }
#pragma unroll
            for (int mi = 0; mi < 4; ++mi)
#pragma unroll
                for (int ni = 0; ni < 4; ++ni)
                    acc[mi][ni] = __builtin_amdgcn_mfma_i32_16x16x64_i8(
                        af[mi], bfr[ni], acc[mi][ni], 0, 0, 0);
        }
        __syncthreads();
    }

    // epilogue: C/D layout col = lane&15, row = (lane>>4)*4 + reg
    // (dtype-independent on gfx950 — m121/m128)
    const float sB_scale = 2.0f / 127.0f;
    const int mrow0 = rowBase + waveM * 64 + (lane >> 4) * 4;
    const int ncol0 = colBase + waveN * 64 + (lane & 15);
#pragma unroll
    for (int mi = 0; mi < 4; ++mi)
#pragma unroll
        for (int ni = 0; ni < 4; ++ni)
#pragma unroll
            for (int rg = 0; rg < 4; ++rg) {
                int rr = mrow0 + mi * 16 + rg;
                int cc = ncol0 + ni * 16;
                float sc = sArow[rr] * sB_scale;
                C[(size_t)rr * NN + cc] = (float)acc[mi][ni][rg] * sc;
            }
}

// ---- fallback: direct O(N^2) eval (only if ws_size is too small) ----
__global__ __launch_bounds__(256) void idct_naive(const float* __restrict__ x,
                                                  float* __restrict__ out) {
    int row = blockIdx.x;
    __shared__ float sx[NN];
    for (int i = threadIdx.x; i < NN; i += 256) sx[i] = x[(size_t)row * NN + i];
    __syncthreads();
    const float s = 3.834951969714103e-4f;  // pi / 8192
    for (int k = threadIdx.x; k < NN; k += 256) {
        int twok1 = 2 * k + 1;
        float acc = sx[0];
        int p = 0;
        for (int n = 1; n < NN; ++n) {
            p += twok1; p &= 16383;
            acc += 2.0f * sx[n] * __cosf((float)p * s);
        }
        out[(size_t)row * NN + k] = acc;
    }
}

extern "C" void kernel_launch(void* const* d_in, const int* in_sizes, int n_in,
                              void* d_out, int out_size, void* d_ws, size_t ws_size,
                              hipStream_t stream) {
    const float* x = (const float*)d_in[0];
    float* out = (float*)d_out;

    const size_t elems = (size_t)NN * NN;
    const size_t need = 2 * elems + NN * sizeof(float);  // 32 MB + 16 KB

    if (ws_size >= need) {
        signed char* Aq = (signed char*)d_ws;
        signed char* Bq = Aq + elems;
        float* sArow = (float*)(Bq + elems);

        prep_i8<<<8192, 256, 0, stream>>>(x, Aq, Bq, sArow);

        dim3 grid(NN / BN, NN / BM);
        idct_gemm<<<grid, 256, 0, stream>>>(Aq, Bq, sArow, out);
    } else {
        idct_naive<<<NN, 256, 0, stream>>>(x, out);
    }
}

// Round 4
// 150.272 us; speedup vs baseline: 1.9703x; 1.2481x over previous
//
#include <hip/hip_runtime.h>
#include <cstdint>

// IDCT (DCT-III) of 4096x4096 fp32 via even/odd decimation + int8 MFMA GEMMs.
//   y_k       = E_k + O_k          (k < N/2)
//   y_{N-1-k} = E_k - O_k
//   E_k = sum_m we_m x[2m]   cos(pi*m*(2k+1)/N)      (we_0=1, else 2)
//   O_k = sum_m 2    x[2m+1] cos(pi*(2m+1)*(2k+1)/(2N))
// Two 4096x2048x2048 i8 GEMMs = HALF the MACs of the direct 4096^3 form.
// R4: same proven R3 tile (XOR-swizzled LDS, 0 bank conflicts, BK=128B rows,
// mfma_i32_16x16x64_i8); each block runs the K-loop twice (E then O) and
// butterflies in the epilogue. Grid 512, 2 blocks/CU (grid-limited).

#define NN 4096
#define HH 2048   // N/2 = K-dim of the split GEMMs and half-spectrum width
#define BM 128
#define BN 128
#define BK 128    // i8 elems per K-step (128 B rows -> identical swizzle geometry)

typedef int i32x4 __attribute__((ext_vector_type(4)));
typedef int i32x2 __attribute__((ext_vector_type(2)));

// async global->LDS, 16B per lane (HW: LDS dest = wave-uniform base + lane*16)
__device__ __forceinline__ void async_copy16(void* lds_base, const void* gptr) {
    __builtin_amdgcn_global_load_lds(
        (const __attribute__((address_space(1))) unsigned int*)gptr,
        (__attribute__((address_space(3))) unsigned int*)lds_base,
        16, 0, 0);
}

__device__ __forceinline__ int pack4(int q0, int q1, int q2, int q3) {
    return (q0 & 255) | ((q1 & 255) << 8) | ((q2 & 255) << 16) | ((q3 & 255) << 24);
}

// ---- prep ----
// blocks 0..4095     : quantize row b of X into Ae (even cols) + Ao (odd cols),
//                      per-row-per-parity scales se[b], so[b]
// blocks 4096..6143  : generate CE row k  (CE[k][m] = we_m cos(pi*m*(2k+1)/N))
// blocks 6144..8191  : generate CO row k  (CO[k][m] = 2 cos(pi*(2m+1)*(2k+1)/2N))
__global__ __launch_bounds__(256) void prep_i8(const float* __restrict__ x,
                                               signed char* __restrict__ Ae,
                                               signed char* __restrict__ Ao,
                                               signed char* __restrict__ CEm,
                                               signed char* __restrict__ COm,
                                               float* __restrict__ se,
                                               float* __restrict__ so) {
    const int b = blockIdx.x;
    const int t = threadIdx.x;
    const float s = 3.834951969714103e-4f;   // pi / 8192

    if (b < 4096) {
        __shared__ float rede[256], redo[256];
        const float* xr = x + (size_t)b * NN;
        float v[16];                          // elements b, n = t*16 .. t*16+15
#pragma unroll
        for (int j = 0; j < 4; ++j) {
            float4 f = ((const float4*)xr)[t * 4 + j];
            v[j * 4 + 0] = f.x; v[j * 4 + 1] = f.y;
            v[j * 4 + 2] = f.z; v[j * 4 + 3] = f.w;
        }
        float emax = 1e-30f, omax = 1e-30f;
#pragma unroll
        for (int i = 0; i < 8; ++i) {
            emax = fmaxf(emax, __builtin_fabsf(v[2 * i]));
            omax = fmaxf(omax, __builtin_fabsf(v[2 * i + 1]));
        }
        rede[t] = emax; redo[t] = omax;
        __syncthreads();
        for (int sr = 128; sr > 0; sr >>= 1) {
            if (t < sr) {
                rede[t] = fmaxf(rede[t], rede[t + sr]);
                redo[t] = fmaxf(redo[t], redo[t + sr]);
            }
            __syncthreads();
        }
        const float rmax_e = rede[0], rmax_o = redo[0];
        const float inv_e = 127.0f / rmax_e, inv_o = 127.0f / rmax_o;
        int qe[8], qo[8];
#pragma unroll
        for (int i = 0; i < 8; ++i) {
            qe[i] = (int)rintf(v[2 * i] * inv_e);
            qo[i] = (int)rintf(v[2 * i + 1] * inv_o);
        }
        i32x2 oe, oo;
        oe[0] = pack4(qe[0], qe[1], qe[2], qe[3]);
        oe[1] = pack4(qe[4], qe[5], qe[6], qe[7]);
        oo[0] = pack4(qo[0], qo[1], qo[2], qo[3]);
        oo[1] = pack4(qo[4], qo[5], qo[6], qo[7]);
        ((i32x2*)(Ae + (size_t)b * HH))[t] = oe;   // m = t*8 .. t*8+7
        ((i32x2*)(Ao + (size_t)b * HH))[t] = oo;
        if (t == 0) {
            se[b] = rmax_e * (1.0f / 127.0f);
            so[b] = rmax_o * (1.0f / 127.0f);
        }
    } else if (b < 6144) {
        const int k = b - 4096;
        const int twok1 = 2 * k + 1;
        int q[8];
#pragma unroll
        for (int i = 0; i < 8; ++i) {
            int m = t * 8 + i;
            int p = (2 * m * twok1) & 16383;            // angle = p * pi/8192
            float w = (m == 0) ? 1.0f : 2.0f;
            q[i] = (int)rintf(w * __cosf((float)p * s) * 63.5f);  // scale 2/127
        }
        i32x2 o;
        o[0] = pack4(q[0], q[1], q[2], q[3]);
        o[1] = pack4(q[4], q[5], q[6], q[7]);
        ((i32x2*)(CEm + (size_t)k * HH))[t] = o;
    } else {
        const int k = b - 6144;
        const int twok1 = 2 * k + 1;
        int q[8];
#pragma unroll
        for (int i = 0; i < 8; ++i) {
            int m = t * 8 + i;
            int p = ((2 * m + 1) * twok1) & 16383;
            q[i] = (int)rintf(__cosf((float)p * s) * 127.0f);     // 2*cos, scale 2/127
        }
        i32x2 o;
        o[0] = pack4(q[0], q[1], q[2], q[3]);
        o[1] = pack4(q[4], q[5], q[6], q[7]);
        ((i32x2*)(COm + (size_t)k * HH))[t] = o;
    }
}

// one full K-pass of the R3-proven tile: acc += A_tile * B_tile^T over K=HH
__device__ __forceinline__ void gemm_pass(const signed char* __restrict__ A,
                                          const signed char* __restrict__ B,
                                          signed char* sA, signed char* sB,
                                          int rowBase, int colBase,
                                          int wave, int lane,
                                          i32x4 (&acc)[4][4]) {
    const int waveM = wave >> 1;
    const int waveN = wave & 1;
    const int srow  = lane >> 3;              // row within 8-row chunk (== r&7)
    const int sgran = lane & 7;               // physical 16B granule lane fills
    const int ggcol = (sgran ^ srow) * 16;    // swizzle baked into global col (bytes)
    const int rmod  = lane & 7;
    const int quad  = lane >> 4;

    for (int k0 = 0; k0 < HH; k0 += BK) {
#pragma unroll
        for (int j = 0; j < 4; ++j) {
            int ck = wave * 4 + j;                // chunk 0..15 (8 rows each)
            int r  = ck * 8 + srow;               // 0..127
            async_copy16(&sA[ck * 1024], A + (size_t)(rowBase + r) * HH + k0 + ggcol);
            async_copy16(&sB[ck * 1024], B + (size_t)(colBase + r) * HH + k0 + ggcol);
        }
        __syncthreads();

#pragma unroll
        for (int kk = 0; kk < 2; ++kk) {
            // logical granule g = kk*4 + quad; physical p = g ^ (r&7)
            const int poff = ((kk * 4 + quad) ^ rmod) * 16;   // bytes
            i32x4 af[4], bfr[4];
#pragma unroll
            for (int mi = 0; mi < 4; ++mi) {
                int r = waveM * 64 + mi * 16 + (lane & 15);
                af[mi] = *(const i32x4*)&sA[r * BK + poff];
            }
#pragma unroll
            for (int ni = 0; ni < 4; ++ni) {
                int r = waveN * 64 + ni * 16 + (lane & 15);
                bfr[ni] = *(const i32x4*)&sB[r * BK + poff];
            }
#pragma unroll
            for (int mi = 0; mi < 4; ++mi)
#pragma unroll
                for (int ni = 0; ni < 4; ++ni)
                    acc[mi][ni] = __builtin_amdgcn_mfma_i32_16x16x64_i8(
                        af[mi], bfr[ni], acc[mi][ni], 0, 0, 0);
        }
        __syncthreads();
    }
}

// ---- split GEMM: accE = Ae*CE^T, accO = Ao*CO^T, butterfly epilogue ----
__global__ __launch_bounds__(256, 2) void idct_gemm2(const signed char* __restrict__ Ae,
                                                     const signed char* __restrict__ Ao,
                                                     const signed char* __restrict__ CEm,
                                                     const signed char* __restrict__ COm,
                                                     const float* __restrict__ se,
                                                     const float* __restrict__ so,
                                                     float* __restrict__ C) {
    __shared__ __align__(16) signed char sA[BM * BK];   // 16 KB
    __shared__ __align__(16) signed char sB[BN * BK];   // 16 KB

    const int tid  = threadIdx.x;
    const int wave = tid >> 6;
    const int lane = tid & 63;

    const int rowBase = blockIdx.y * BM;        // output rows
    const int colBase = blockIdx.x * BN;        // half-spectrum cols k in [0,2048)

    i32x4 accE[4][4] = {};
    gemm_pass(Ae, CEm, sA, sB, rowBase, colBase, wave, lane, accE);
    i32x4 accO[4][4] = {};
    gemm_pass(Ao, COm, sA, sB, rowBase, colBase, wave, lane, accO);

    // epilogue: C/D layout col = lane&15, row = (lane>>4)*4 + reg; butterfly
    const float sB_s = 2.0f / 127.0f;
    const int mrow0 = rowBase + (wave >> 1) * 64 + (lane >> 4) * 4;
    const int ncol0 = colBase + (wave & 1) * 64 + (lane & 15);
#pragma unroll
    for (int mi = 0; mi < 4; ++mi)
#pragma unroll
        for (int ni = 0; ni < 4; ++ni)
#pragma unroll
            for (int rg = 0; rg < 4; ++rg) {
                int rr = mrow0 + mi * 16 + rg;
                int cc = ncol0 + ni * 16;
                float e = (float)accE[mi][ni][rg] * (se[rr] * sB_s);
                float o = (float)accO[mi][ni][rg] * (so[rr] * sB_s);
                C[(size_t)rr * NN + cc] = e + o;
                C[(size_t)rr * NN + (NN - 1 - cc)] = e - o;
            }
}

// ---- fallback: direct O(N^2) eval (only if ws_size is too small) ----
__global__ __launch_bounds__(256) void idct_naive(const float* __restrict__ x,
                                                  float* __restrict__ out) {
    int row = blockIdx.x;
    __shared__ float sx[NN];
    for (int i = threadIdx.x; i < NN; i += 256) sx[i] = x[(size_t)row * NN + i];
    __syncthreads();
    const float s = 3.834951969714103e-4f;  // pi / 8192
    for (int k = threadIdx.x; k < NN; k += 256) {
        int twok1 = 2 * k + 1;
        float acc = sx[0];
        int p = 0;
        for (int n = 1; n < NN; ++n) {
            p += twok1; p &= 16383;
            acc += 2.0f * sx[n] * __cosf((float)p * s);
        }
        out[(size_t)row * NN + k] = acc;
    }
}

extern "C" void kernel_launch(void* const* d_in, const int* in_sizes, int n_in,
                              void* d_out, int out_size, void* d_ws, size_t ws_size,
                              hipStream_t stream) {
    const float* x = (const float*)d_in[0];
    float* out = (float*)d_out;

    const size_t eA = (size_t)NN * HH;          // 8 MB each for Ae/Ao
    const size_t eC = (size_t)HH * HH;          // 4 MB each for CE/CO
    const size_t need = 2 * eA + 2 * eC + 2 * NN * sizeof(float);

    if (ws_size >= need) {
        signed char* Ae = (signed char*)d_ws;
        signed char* Ao = Ae + eA;
        signed char* CEm = Ao + eA;
        signed char* COm = CEm + eC;
        float* se = (float*)(COm + eC);
        float* so = se + NN;

        prep_i8<<<8192, 256, 0, stream>>>(x, Ae, Ao, CEm, COm, se, so);

        dim3 grid(HH / BN, NN / BM);            // (16, 32) = 512 blocks
        idct_gemm2<<<grid, 256, 0, stream>>>(Ae, Ao, CEm, COm, se, so, out);
    } else {
        idct_naive<<<NN, 256, 0, stream>>>(x, out);
    }
}

// Round 5
// 146.432 us; speedup vs baseline: 2.0220x; 1.0262x over previous
//
#include <hip/hip_runtime.h>
#include <cstdint>

// IDCT (DCT-III) of 4096x4096 fp32 via even/odd decimation + int8 MFMA GEMMs.
//   y_k       = E_k + O_k          (k < N/2)
//   y_{N-1-k} = E_k - O_k
//   E_k = sum_m we_m x[2m]   cos(pi*m*(2k+1)/N)      (we_0=1, else 2)
//   O_k = sum_m 2    x[2m+1] cos(pi*(2m+1)*(2k+1)/(2N))
// R5: E and O GEMMs interleaved in ONE K-loop (4 tiles in 64 KB LDS) ->
// half the barriers of R4's two sequential passes. Grid 512 = 2 blocks/CU
// (grid-limited), 64 KB LDS still allows 2/CU. prep: wave-shuffle row-max
// (1 barrier) instead of 9-barrier LDS tree.

#define NN 4096
#define HH 2048   // N/2 = K-dim of the split GEMMs and half-spectrum width
#define BM 128
#define BN 128
#define BK 128    // i8 elems per K-step (128 B rows -> proven swizzle geometry)

typedef int i32x4 __attribute__((ext_vector_type(4)));
typedef int i32x2 __attribute__((ext_vector_type(2)));

// async global->LDS, 16B per lane (HW: LDS dest = wave-uniform base + lane*16)
__device__ __forceinline__ void async_copy16(void* lds_base, const void* gptr) {
    __builtin_amdgcn_global_load_lds(
        (const __attribute__((address_space(1))) unsigned int*)gptr,
        (__attribute__((address_space(3))) unsigned int*)lds_base,
        16, 0, 0);
}

__device__ __forceinline__ int pack4(int q0, int q1, int q2, int q3) {
    return (q0 & 255) | ((q1 & 255) << 8) | ((q2 & 255) << 16) | ((q3 & 255) << 24);
}

// ---- prep ----
// blocks 0..4095     : quantize row b of X into Ae (even cols) + Ao (odd cols),
//                      per-row-per-parity scales se[b], so[b]
// blocks 4096..6143  : CE row k  (CE[k][m] = we_m cos(pi*m*(2k+1)/N))
// blocks 6144..8191  : CO row k  (CO[k][m] = 2 cos(pi*(2m+1)*(2k+1)/2N))
__global__ __launch_bounds__(256) void prep_i8(const float* __restrict__ x,
                                               signed char* __restrict__ Ae,
                                               signed char* __restrict__ Ao,
                                               signed char* __restrict__ CEm,
                                               signed char* __restrict__ COm,
                                               float* __restrict__ se,
                                               float* __restrict__ so) {
    const int b = blockIdx.x;
    const int t = threadIdx.x;
    const float s = 3.834951969714103e-4f;   // pi / 8192

    if (b < 4096) {
        __shared__ float wmaxe[4], wmaxo[4];
        const float* xr = x + (size_t)b * NN;
        float v[16];                          // elements n = t*16 .. t*16+15
#pragma unroll
        for (int j = 0; j < 4; ++j) {
            float4 f = ((const float4*)xr)[t * 4 + j];
            v[j * 4 + 0] = f.x; v[j * 4 + 1] = f.y;
            v[j * 4 + 2] = f.z; v[j * 4 + 3] = f.w;
        }
        float emax = 1e-30f, omax = 1e-30f;
#pragma unroll
        for (int i = 0; i < 8; ++i) {
            emax = fmaxf(emax, __builtin_fabsf(v[2 * i]));
            omax = fmaxf(omax, __builtin_fabsf(v[2 * i + 1]));
        }
        // 64-lane butterfly reduce (no barrier)
#pragma unroll
        for (int m = 1; m < 64; m <<= 1) {
            emax = fmaxf(emax, __shfl_xor(emax, m));
            omax = fmaxf(omax, __shfl_xor(omax, m));
        }
        const int wv = t >> 6;
        if ((t & 63) == 0) { wmaxe[wv] = emax; wmaxo[wv] = omax; }
        __syncthreads();
        const float rmax_e = fmaxf(fmaxf(wmaxe[0], wmaxe[1]), fmaxf(wmaxe[2], wmaxe[3]));
        const float rmax_o = fmaxf(fmaxf(wmaxo[0], wmaxo[1]), fmaxf(wmaxo[2], wmaxo[3]));
        const float inv_e = 127.0f / rmax_e, inv_o = 127.0f / rmax_o;
        int qe[8], qo[8];
#pragma unroll
        for (int i = 0; i < 8; ++i) {
            qe[i] = (int)rintf(v[2 * i] * inv_e);
            qo[i] = (int)rintf(v[2 * i + 1] * inv_o);
        }
        i32x2 oe, oo;
        oe[0] = pack4(qe[0], qe[1], qe[2], qe[3]);
        oe[1] = pack4(qe[4], qe[5], qe[6], qe[7]);
        oo[0] = pack4(qo[0], qo[1], qo[2], qo[3]);
        oo[1] = pack4(qo[4], qo[5], qo[6], qo[7]);
        ((i32x2*)(Ae + (size_t)b * HH))[t] = oe;   // m = t*8 .. t*8+7
        ((i32x2*)(Ao + (size_t)b * HH))[t] = oo;
        if (t == 0) {
            se[b] = rmax_e * (1.0f / 127.0f);
            so[b] = rmax_o * (1.0f / 127.0f);
        }
    } else if (b < 6144) {
        const int k = b - 4096;
        const int twok1 = 2 * k + 1;
        int q[8];
#pragma unroll
        for (int i = 0; i < 8; ++i) {
            int m = t * 8 + i;
            int p = (2 * m * twok1) & 16383;            // angle = p * pi/8192
            float w = (m == 0) ? 1.0f : 2.0f;
            q[i] = (int)rintf(w * __cosf((float)p * s) * 63.5f);  // scale 2/127
        }
        i32x2 o;
        o[0] = pack4(q[0], q[1], q[2], q[3]);
        o[1] = pack4(q[4], q[5], q[6], q[7]);
        ((i32x2*)(CEm + (size_t)k * HH))[t] = o;
    } else {
        const int k = b - 6144;
        const int twok1 = 2 * k + 1;
        int q[8];
#pragma unroll
        for (int i = 0; i < 8; ++i) {
            int m = t * 8 + i;
            int p = ((2 * m + 1) * twok1) & 16383;
            q[i] = (int)rintf(__cosf((float)p * s) * 127.0f);     // 2*cos, scale 2/127
        }
        i32x2 o;
        o[0] = pack4(q[0], q[1], q[2], q[3]);
        o[1] = pack4(q[4], q[5], q[6], q[7]);
        ((i32x2*)(COm + (size_t)k * HH))[t] = o;
    }
}

// ---- fused split GEMM: accE = Ae*CE^T and accO = Ao*CO^T in one K-loop ----
// 128x128 tile, BK=128, 4 waves 2x2, each wave 4x4 grid of 16x16x64 MFMA per
// branch. XOR-swizzled LDS (granule g of row r at g^(r&7)) -> 0 conflicts.
__global__ __launch_bounds__(256, 2) void idct_gemm2(const signed char* __restrict__ Ae,
                                                     const signed char* __restrict__ Ao,
                                                     const signed char* __restrict__ CEm,
                                                     const signed char* __restrict__ COm,
                                                     const float* __restrict__ se,
                                                     const float* __restrict__ so,
                                                     float* __restrict__ C) {
    __shared__ __align__(16) signed char sAe[BM * BK];   // 16 KB
    __shared__ __align__(16) signed char sAo[BM * BK];   // 16 KB
    __shared__ __align__(16) signed char sCE[BN * BK];   // 16 KB
    __shared__ __align__(16) signed char sCO[BN * BK];   // 16 KB  (total 64 KB)

    const int tid  = threadIdx.x;
    const int wave = tid >> 6;
    const int lane = tid & 63;
    const int waveM = wave >> 1;
    const int waveN = wave & 1;

    const int rowBase = blockIdx.y * BM;        // output rows
    const int colBase = blockIdx.x * BN;        // half-spectrum cols k in [0,2048)

    i32x4 accE[4][4] = {};
    i32x4 accO[4][4] = {};

    // staging: chunk = 1 KB = 8 rows x 8 granules(16B); 16 chunks per matrix
    const int srow  = lane >> 3;              // row within chunk (== r&7)
    const int sgran = lane & 7;               // physical granule this lane fills
    const int ggcol = (sgran ^ srow) * 16;    // swizzle baked into global col (bytes)
    const int rmod  = lane & 7;
    const int quad  = lane >> 4;

    for (int k0 = 0; k0 < HH; k0 += BK) {
#pragma unroll
        for (int j = 0; j < 4; ++j) {
            int ck = wave * 4 + j;                // chunk 0..15 (8 rows each)
            int r  = ck * 8 + srow;               // 0..127
            size_t aoff = (size_t)(rowBase + r) * HH + k0 + ggcol;
            size_t boff = (size_t)(colBase + r) * HH + k0 + ggcol;
            async_copy16(&sAe[ck * 1024], Ae + aoff);
            async_copy16(&sAo[ck * 1024], Ao + aoff);
            async_copy16(&sCE[ck * 1024], CEm + boff);
            async_copy16(&sCO[ck * 1024], COm + boff);
        }
        __syncthreads();

#pragma unroll
        for (int kk = 0; kk < 2; ++kk) {
            // logical granule g = kk*4 + quad; physical p = g ^ (r&7)
            const int poff = ((kk * 4 + quad) ^ rmod) * 16;   // bytes
            {
                i32x4 af[4], bfr[4];
#pragma unroll
                for (int mi = 0; mi < 4; ++mi) {
                    int r = waveM * 64 + mi * 16 + (lane & 15);
                    af[mi] = *(const i32x4*)&sAe[r * BK + poff];
                }
#pragma unroll
                for (int ni = 0; ni < 4; ++ni) {
                    int r = waveN * 64 + ni * 16 + (lane & 15);
                    bfr[ni] = *(const i32x4*)&sCE[r * BK + poff];
                }
#pragma unroll
                for (int mi = 0; mi < 4; ++mi)
#pragma unroll
                    for (int ni = 0; ni < 4; ++ni)
                        accE[mi][ni] = __builtin_amdgcn_mfma_i32_16x16x64_i8(
                            af[mi], bfr[ni], accE[mi][ni], 0, 0, 0);
            }
            {
                i32x4 af[4], bfr[4];
#pragma unroll
                for (int mi = 0; mi < 4; ++mi) {
                    int r = waveM * 64 + mi * 16 + (lane & 15);
                    af[mi] = *(const i32x4*)&sAo[r * BK + poff];
                }
#pragma unroll
                for (int ni = 0; ni < 4; ++ni) {
                    int r = waveN * 64 + ni * 16 + (lane & 15);
                    bfr[ni] = *(const i32x4*)&sCO[r * BK + poff];
                }
#pragma unroll
                for (int mi = 0; mi < 4; ++mi)
#pragma unroll
                    for (int ni = 0; ni < 4; ++ni)
                        accO[mi][ni] = __builtin_amdgcn_mfma_i32_16x16x64_i8(
                            af[mi], bfr[ni], accO[mi][ni], 0, 0, 0);
            }
        }
        __syncthreads();
    }

    // epilogue: C/D layout col = lane&15, row = (lane>>4)*4 + reg; butterfly
    const float sB_s = 2.0f / 127.0f;
    const int mrow0 = rowBase + waveM * 64 + (lane >> 4) * 4;
    const int ncol0 = colBase + waveN * 64 + (lane & 15);
#pragma unroll
    for (int mi = 0; mi < 4; ++mi)
#pragma unroll
        for (int ni = 0; ni < 4; ++ni)
#pragma unroll
            for (int rg = 0; rg < 4; ++rg) {
                int rr = mrow0 + mi * 16 + rg;
                int cc = ncol0 + ni * 16;
                float e = (float)accE[mi][ni][rg] * (se[rr] * sB_s);
                float o = (float)accO[mi][ni][rg] * (so[rr] * sB_s);
                C[(size_t)rr * NN + cc] = e + o;
                C[(size_t)rr * NN + (NN - 1 - cc)] = e - o;
            }
}

// ---- fallback: direct O(N^2) eval (only if ws_size is too small) ----
__global__ __launch_bounds__(256) void idct_naive(const float* __restrict__ x,
                                                  float* __restrict__ out) {
    int row = blockIdx.x;
    __shared__ float sx[NN];
    for (int i = threadIdx.x; i < NN; i += 256) sx[i] = x[(size_t)row * NN + i];
    __syncthreads();
    const float s = 3.834951969714103e-4f;  // pi / 8192
    for (int k = threadIdx.x; k < NN; k += 256) {
        int twok1 = 2 * k + 1;
        float acc = sx[0];
        int p = 0;
        for (int n = 1; n < NN; ++n) {
            p += twok1; p &= 16383;
            acc += 2.0f * sx[n] * __cosf((float)p * s);
        }
        out[(size_t)row * NN + k] = acc;
    }
}

extern "C" void kernel_launch(void* const* d_in, const int* in_sizes, int n_in,
                              void* d_out, int out_size, void* d_ws, size_t ws_size,
                              hipStream_t stream) {
    const float* x = (const float*)d_in[0];
    float* out = (float*)d_out;

    const size_t eA = (size_t)NN * HH;          // 8 MB each for Ae/Ao
    const size_t eC = (size_t)HH * HH;          // 4 MB each for CE/CO
    const size_t need = 2 * eA + 2 * eC + 2 * NN * sizeof(float);

    if (ws_size >= need) {
        signed char* Ae = (signed char*)d_ws;
        signed char* Ao = Ae + eA;
        signed char* CEm = Ao + eA;
        signed char* COm = CEm + eC;
        float* se = (float*)(COm + eC);
        float* so = se + NN;

        prep_i8<<<8192, 256, 0, stream>>>(x, Ae, Ao, CEm, COm, se, so);

        dim3 grid(HH / BN, NN / BM);            // (16, 32) = 512 blocks
        idct_gemm2<<<grid, 256, 0, stream>>>(Ae, Ao, CEm, COm, se, so, out);
    } else {
        idct_naive<<<NN, 256, 0, stream>>>(x, out);
    }
}